// Round 4
// baseline (5091.109 us; speedup 1.0000x reference)
//
#include <hip/hip_runtime.h>
#include <hip/hip_fp16.h>

// LSTM forecast: B=256, T_past=512, HID=512, FEAT=1, future=64 -> 576 steps.
// Grid 256 WGs = 16 batch-groups (bb) x 16 hidden-groups (gb), 1 WG/CU.
// Each WG: 16 batch x 32 hidden. W_hh slice persistent in registers as fp16
// MFMA B-frags.
//
// R1: no ordered agent atomics / __threadfence (buffer_wbl2/inv = whole-L2
//     flush, ~20us/step). All cross-WG traffic = RELAXED agent-scope.
// R2: 2380us. latency-bound, ~4us/step of serial MALL round trips.
// R3: 2577us. flag-line barrier neutral; gb==0 per-step decoder dot was a
//     straggler (group barrier couples to slowest WG) — reverted.
// R4: per-WAVE protocol: each wave drains its own h stores (wave-local
//     s_waitcnt), posts its own flag (64 flags/group), polls independently,
//     loads its own 4-row LDS quarter. 2 WG barriers/step (was 4). out[] via
//     balanced fire-and-forget atomicAdd partials (R2 style).

#define TPAST 512
#define TTOT  576
#define HIDN  512
#define BW    16            // batch per WG
#define HW    32            // hidden per WG
#define HSTR  520           // hcur LDS row stride (fp16); *2B=1040, 16B-aligned
#define HSTR64 130          // hcur row stride in u64
#define GSTR  133           // gates LDS row stride (fp32)
#define BATCHN 256

typedef _Float16 half8   __attribute__((ext_vector_type(8)));
typedef _Float16 half2v  __attribute__((ext_vector_type(2)));
typedef float    float4v __attribute__((ext_vector_type(4)));

__device__ __forceinline__ float fast_exp(float x) {
    return __builtin_amdgcn_exp2f(x * 1.44269504f);
}
__device__ __forceinline__ float fast_sigmoid(float x) {
    return __builtin_amdgcn_rcpf(1.0f + fast_exp(-x));
}
__device__ __forceinline__ float fast_tanh(float x) {
    return 1.0f - 2.0f * __builtin_amdgcn_rcpf(fast_exp(2.0f * x) + 1.0f);
}

__global__ __launch_bounds__(256, 1)
void lstm_forecast_kernel(const float* __restrict__ xseq,
                          const float* __restrict__ Wih,
                          const float* __restrict__ Whh,
                          const float* __restrict__ bih,
                          const float* __restrict__ bhh,
                          const float* __restrict__ Wdec,
                          const float* __restrict__ bdec,
                          float* __restrict__ out,
                          unsigned int* __restrict__ flagbase,
                          unsigned int* __restrict__ hbuf)   // fp16 pairs, [2][256][512]
{
    __shared__ _Float16 hcur[BW * HSTR];   // current h tile, fp16, row=batch
    __shared__ float    gates[BW * GSTR];  // staged MFMA output (16 x 128)
    __shared__ float    wdecs[HIDN];       // W_dec row
    __shared__ float    xcur[BW];

    const int tid  = threadIdx.x;
    const int bb   = blockIdx.x & 15;      // batch group
    const int gb   = blockIdx.x >> 4;      // hidden group
    const int lane = tid & 63;
    const int wave = tid >> 6;
    const int m    = lane & 15;            // MFMA A-row / D-col
    const int q    = lane >> 4;            // MFMA quad

    // ---- persistent W_hh B-fragments: 2 col-blocks x 16 k-steps ----
    half8 Wf[2][16];
    {
        #pragma unroll
        for (int cbi = 0; cbi < 2; ++cbi) {
            const int col = (2 * wave + cbi) * 16 + m;        // 0..127
            const int gt  = col >> 5;                          // 0=i 1=f 2=g 3=o
            const int jl  = col & 31;
            const float* wr = Whh + (gt * HIDN + gb * HW + jl) * HIDN;
            #pragma unroll
            for (int kk = 0; kk < 16; ++kk) {
                const int k0 = kk * 32 + q * 8;
                float4v u = *(const float4v*)(wr + k0);
                float4v v = *(const float4v*)(wr + k0 + 4);
                half8 h;
                h[0] = (_Float16)u[0]; h[1] = (_Float16)u[1];
                h[2] = (_Float16)u[2]; h[3] = (_Float16)u[3];
                h[4] = (_Float16)v[0]; h[5] = (_Float16)v[1];
                h[6] = (_Float16)v[2]; h[7] = (_Float16)v[3];
                Wf[cbi][kk] = h;
            }
        }
    }

    // ---- per-thread elementwise constants ----
    const int eb = tid >> 4;               // batch row (wave w owns rows 4w..4w+3)
    const int jj = tid & 15;
    const int j0 = 2 * jj;
    float wih_r[2][4], bsum_r[2][4], wd[2];
    #pragma unroll
    for (int p = 0; p < 2; ++p) {
        const int jg = gb * HW + j0 + p;
        #pragma unroll
        for (int gt = 0; gt < 4; ++gt) {
            const int r = gt * HIDN + jg;
            wih_r[p][gt]  = Wih[r];
            bsum_r[p][gt] = bih[r] + bhh[r];
        }
        wd[p] = Wdec[jg];
    }
    const float bdecv = bdec[0];
    float c0 = 0.01f, c1 = 0.01f;

    // ---- init ----
    {
        const _Float16 hinit = (_Float16)0.01f;
        for (int i = tid; i < BW * HSTR; i += 256) hcur[i] = hinit;
        for (int i = tid; i < HIDN; i += 256) wdecs[i] = Wdec[i];
        if (tid < BW) xcur[tid] = xseq[(bb * BW + tid) * TPAST + 0];
    }
    __syncthreads();

    unsigned int* gflags = flagbase + bb * 64;   // 64 u32 per group (16 WG x 4 waves)
    const int bglob_e = bb * BW + eb;

    for (int t = 0; t < TTOT; ++t) {
        // ---- phase 1: MFMA  gates_tile = h (16x512) * W^T (512x128) ----
        float4v acc0 = {0.f, 0.f, 0.f, 0.f};
        float4v acc1 = {0.f, 0.f, 0.f, 0.f};
        const _Float16* arow = hcur + m * HSTR + q * 8;
        #pragma unroll
        for (int kk = 0; kk < 16; ++kk) {
            half8 af = *(const half8*)(arow + kk * 32);
            acc0 = __builtin_amdgcn_mfma_f32_16x16x32_f16(af, Wf[0][kk], acc0, 0, 0, 0);
            acc1 = __builtin_amdgcn_mfma_f32_16x16x32_f16(af, Wf[1][kk], acc1, 0, 0, 0);
        }
        // ---- phase 2: stage gates to LDS (C layout: col=m, row=q*4+r) ----
        {
            const int colbase = wave * 32;
            #pragma unroll
            for (int r = 0; r < 4; ++r) {
                gates[(q * 4 + r) * GSTR + colbase +      m] = acc0[r];
                gates[(q * 4 + r) * GSTR + colbase + 16 + m] = acc1[r];
            }
        }
        // prefetch next past-input (latency hides under drain below)
        const int tn = t + 1;
        float xq = 0.f;
        if (tn < TPAST && tid < BW) xq = xseq[(bb * BW + tid) * TPAST + tn];

        __syncthreads();   // barrier A: gates complete

        // ---- phase 3: elementwise LSTM + h store + out partial (fire&forget) ----
        {
            const float xc = xcur[eb];
            const float* grow = gates + eb * GSTR;

            float gi = grow[      j0] + xc * wih_r[0][0] + bsum_r[0][0];
            float gf = grow[32  + j0] + xc * wih_r[0][1] + bsum_r[0][1];
            float gg = grow[64  + j0] + xc * wih_r[0][2] + bsum_r[0][2];
            float go = grow[96  + j0] + xc * wih_r[0][3] + bsum_r[0][3];
            c0 = fast_sigmoid(gf) * c0 + fast_sigmoid(gi) * fast_tanh(gg);
            const float h0 = fast_sigmoid(go) * fast_tanh(c0);

            gi = grow[      j0 + 1] + xc * wih_r[1][0] + bsum_r[1][0];
            gf = grow[32  + j0 + 1] + xc * wih_r[1][1] + bsum_r[1][1];
            gg = grow[64  + j0 + 1] + xc * wih_r[1][2] + bsum_r[1][2];
            go = grow[96  + j0 + 1] + xc * wih_r[1][3] + bsum_r[1][3];
            c1 = fast_sigmoid(gf) * c1 + fast_sigmoid(gi) * fast_tanh(gg);
            const float h1 = fast_sigmoid(go) * fast_tanh(c1);

            half2v hp; hp[0] = (_Float16)h0; hp[1] = (_Float16)h1;
            const unsigned int bits = __builtin_bit_cast(unsigned int, hp);
            unsigned int* hdst = hbuf
                + (size_t)((tn & 1) * BATCHN + bglob_e) * (HIDN / 2)
                + gb * (HW / 2) + jj;
            __hip_atomic_store(hdst, bits, __ATOMIC_RELAXED,
                               __HIP_MEMORY_SCOPE_AGENT);

            // balanced decoder partial -> out (nothing on-device reads out)
            float dp = h0 * wd[0] + h1 * wd[1];
            dp += __shfl_down(dp, 8);
            dp += __shfl_down(dp, 4);
            dp += __shfl_down(dp, 2);
            dp += __shfl_down(dp, 1);
            if (jj == 0)
                atomicAdd(out + bglob_e * TTOT + t,
                          dp + (gb == 0 ? bdecv : 0.0f));
        }

        if (t == TTOT - 1) break;

        // ---- phase 4: per-wave drain -> flag -> poll (no WG barrier) ----
        const unsigned int target = (unsigned int)tn;
        __atomic_signal_fence(__ATOMIC_SEQ_CST);
        __builtin_amdgcn_s_waitcnt(0);          // wave-local: h stores at MALL
        __atomic_signal_fence(__ATOMIC_SEQ_CST);
        if (lane == 0)
            __hip_atomic_store(gflags + gb * 4 + wave, target,
                               __ATOMIC_RELAXED, __HIP_MEMORY_SCOPE_AGENT);
        {
            const unsigned int* slot = gflags + lane;   // 64 flags, 1 per lane
            int guard = 0;
            for (;;) {
                const unsigned int v = __hip_atomic_load(
                    slot, __ATOMIC_RELAXED, __HIP_MEMORY_SCOPE_AGENT);
                if (__ballot(v >= target) == ~0ull) break;
                __builtin_amdgcn_s_sleep(1);
                if (++guard > (1 << 22)) break;   // fail loud, not hung
            }
        }
        __builtin_amdgcn_sched_barrier(0);   // keep reload below the spin

        // ---- phase 5: per-wave reload of its 4 rows (4 x 512 fp16) ----
        // Safe to overwrite hcur without a barrier: every flag>=tn implies that
        // wave passed barrier A, which implies all waves finished phase-1 reads.
        {
            const int p1 = tn & 1;
            const unsigned long long* hsrc = (const unsigned long long*)hbuf
                + (size_t)(p1 * BATCHN + bb * BW) * (HIDN / 4);
            unsigned long long* hc64 = (unsigned long long*)hcur;
            const int r  = wave * 4 + (lane >> 4);   // row 0..15
            const int cb = lane & 15;
            #pragma unroll
            for (int i = 0; i < 8; ++i) {
                const int col = cb + 16 * i;         // 0..127 u64
                hc64[r * HSTR64 + col] =
                    __hip_atomic_load(hsrc + r * (HIDN / 4) + col,
                                      __ATOMIC_RELAXED, __HIP_MEMORY_SCOPE_AGENT);
            }
        }
        __syncthreads();   // barrier B: hcur complete

        // ---- phase 6: next x ----
        if (tn >= TPAST) {
            // x_{tn} = h_{tn} . W_dec + b_dec from the fresh tile (all WGs)
            const _Float16* hr = hcur + eb * HSTR + jj * 32;
            const float*    wr = wdecs + jj * 32;
            float dx = 0.f;
            #pragma unroll
            for (int u = 0; u < 4; ++u) {
                half8 hv = *(const half8*)(hr + u * 8);
                #pragma unroll
                for (int e = 0; e < 8; ++e)
                    dx += (float)hv[e] * wr[u * 8 + e];
            }
            dx += __shfl_down(dx, 8);
            dx += __shfl_down(dx, 4);
            dx += __shfl_down(dx, 2);
            dx += __shfl_down(dx, 1);
            if (jj == 0) xcur[eb] = dx + bdecv;   // writer+readers in same wave
        } else {
            if (tid < BW) xcur[tid] = xq;  // cross-wave reads ordered by next barrier A
        }
    }
}

extern "C" void kernel_launch(void* const* d_in, const int* in_sizes, int n_in,
                              void* d_out, int out_size, void* d_ws, size_t ws_size,
                              hipStream_t stream) {
    (void)in_sizes; (void)n_in; (void)ws_size;
    const float* xseq = (const float*)d_in[0];
    // d_in[1] = future_n scalar (fixed 64, shapes hardcoded)
    const float* Wih  = (const float*)d_in[2];
    const float* Whh  = (const float*)d_in[3];
    const float* bih  = (const float*)d_in[4];
    const float* bhh  = (const float*)d_in[5];
    const float* Wdec = (const float*)d_in[6];
    const float* bdec = (const float*)d_in[7];
    float* out = (float*)d_out;

    unsigned int* flags = (unsigned int*)d_ws;                // 16 groups x 256B
    unsigned int* hbuf  = (unsigned int*)((char*)d_ws + 8192);// [2][256][512] fp16 pairs

    hipMemsetAsync(d_ws, 0, 8192, stream);
    hipMemsetAsync(d_out, 0, (size_t)out_size * sizeof(float), stream);
    lstm_forecast_kernel<<<dim3(256), dim3(256), 0, stream>>>(
        xseq, Wih, Whh, bih, bhh, Wdec, bdec, out, flags, hbuf);
}

// Round 5
// 1967.858 us; speedup vs baseline: 2.5871x; 2.5871x over previous
//
#include <hip/hip_runtime.h>
#include <hip/hip_fp16.h>

// LSTM forecast: B=256, T_past=512, HID=512, FEAT=1, future=64 -> 576 steps.
// R5 grid: 128 WGs x 512 threads = 16 batch-groups (bb) x 8 hidden-groups (gb).
// Each WG: 16 batch x 64 hidden, W_hh slice (256 rows x 512 k) persistent in
// registers as fp16 MFMA B-frags (128 VGPRs/thread).
//
// Lessons:
// R1: ordered agent atomics / __threadfence emit buffer_wbl2/inv (whole-L2
//     flush, ~20us/step). Everything cross-WG is RELAXED agent-scope.
// R2 (2380us): 1 poller/WG + RMW arrive. Exchange is served XCD-locally by L2
//     (groups bb=blockIdx&15 are XCD-local under round-robin; FETCH shows no
//     reload traffic reaching EA).
// R3 (2577us): flag-store arrive fine; per-step gb0 decoder dot = straggler.
// R4 (5091us): per-WAVE flags/polls = 4x pollers + 4x flag footprint ->
//     contention. Poller count and flag-line footprint dominate.
// R5: 8-WG groups (512-thr WGs), flag-store arrive (1 store/WG), poll = every
//     wave loads one 32B flag line, deferred out-atomics (drain off the
//     critical path), 3 barriers/step.

#define TPAST 512
#define TTOT  576
#define HIDN  512
#define BW    16            // batch per WG
#define HW    64            // hidden per WG
#define NGRP  8             // WGs per batch group
#define NTHR  512
#define HSTR  520           // hcur LDS row stride (fp16); *2B=1040, 16B-aligned
#define HSTR64 130          // hcur row stride in u64
#define GSTR  261           // gates LDS row stride (fp32); 2-way max on reads
#define BATCHN 256

typedef _Float16 half8   __attribute__((ext_vector_type(8)));
typedef _Float16 half2v  __attribute__((ext_vector_type(2)));
typedef float    float4v __attribute__((ext_vector_type(4)));

__device__ __forceinline__ float fast_exp(float x) {
    return __builtin_amdgcn_exp2f(x * 1.44269504f);
}
__device__ __forceinline__ float fast_sigmoid(float x) {
    return __builtin_amdgcn_rcpf(1.0f + fast_exp(-x));
}
__device__ __forceinline__ float fast_tanh(float x) {
    return 1.0f - 2.0f * __builtin_amdgcn_rcpf(fast_exp(2.0f * x) + 1.0f);
}

__global__ __launch_bounds__(NTHR, 1)
void lstm_forecast_kernel(const float* __restrict__ xseq,
                          const float* __restrict__ Wih,
                          const float* __restrict__ Whh,
                          const float* __restrict__ bih,
                          const float* __restrict__ bhh,
                          const float* __restrict__ Wdec,
                          const float* __restrict__ bdec,
                          float* __restrict__ out,
                          unsigned int* __restrict__ flagbase,
                          unsigned int* __restrict__ hbuf)   // fp16 pairs, [2][256][512]
{
    __shared__ _Float16 hcur[BW * HSTR];   // current h tile, fp16, row=batch
    __shared__ float    gates[BW * GSTR];  // staged MFMA output (16 x 256)
    __shared__ float    wdecs[HIDN];       // W_dec row
    __shared__ float    xcur[BW];

    const int tid  = threadIdx.x;
    const int bb   = blockIdx.x & 15;      // batch group (XCD-local: 16 == 0 mod 8)
    const int gb   = blockIdx.x >> 4;      // hidden group 0..7
    const int lane = tid & 63;
    const int wave = tid >> 6;             // 0..7
    const int m    = lane & 15;            // MFMA A-row / D-col
    const int q    = lane >> 4;            // MFMA quad

    // ---- persistent W_hh B-fragments: 2 col-blocks x 16 k-steps (128 VGPRs) ----
    half8 Wf[2][16];
    {
        #pragma unroll
        for (int cbi = 0; cbi < 2; ++cbi) {
            const int col = (2 * wave + cbi) * 16 + m;        // 0..255
            const int gt  = col >> 6;                          // 0=i 1=f 2=g 3=o
            const int jl  = col & 63;
            const float* wr = Whh + (size_t)(gt * HIDN + gb * HW + jl) * HIDN;
            #pragma unroll
            for (int kk = 0; kk < 16; ++kk) {
                const int k0 = kk * 32 + q * 8;
                float4v u = *(const float4v*)(wr + k0);
                float4v v = *(const float4v*)(wr + k0 + 4);
                half8 h;
                h[0] = (_Float16)u[0]; h[1] = (_Float16)u[1];
                h[2] = (_Float16)u[2]; h[3] = (_Float16)u[3];
                h[4] = (_Float16)v[0]; h[5] = (_Float16)v[1];
                h[6] = (_Float16)v[2]; h[7] = (_Float16)v[3];
                Wf[cbi][kk] = h;
            }
        }
    }

    // ---- per-thread elementwise constants: thread -> (batch eb, hidden j0,j0+1)
    const int eb = tid >> 5;               // 0..15 (wave w owns rows 2w,2w+1)
    const int jj = tid & 31;
    const int j0 = 2 * jj;                 // 0..62
    float wih_r[2][4], bsum_r[2][4], wd[2];
    #pragma unroll
    for (int p = 0; p < 2; ++p) {
        const int jg = gb * HW + j0 + p;
        #pragma unroll
        for (int gt = 0; gt < 4; ++gt) {
            const int r = gt * HIDN + jg;
            wih_r[p][gt]  = Wih[r];
            bsum_r[p][gt] = bih[r] + bhh[r];
        }
        wd[p] = Wdec[jg];
    }
    const float bdecv = bdec[0];
    float c0 = 0.01f, c1 = 0.01f;

    // ---- init ----
    {
        const _Float16 hinit = (_Float16)0.01f;
        for (int i = tid; i < BW * HSTR; i += NTHR) hcur[i] = hinit;
        wdecs[tid] = Wdec[tid];            // HIDN == NTHR
        if (tid < BW) xcur[tid] = xseq[(bb * BW + tid) * TPAST + 0];
    }
    __syncthreads();

    unsigned int* gflags = flagbase + bb * 16;   // 64B line/group, slots 0..7
    const int bglob_e = bb * BW + eb;
    const bool dp_lead = ((lane & 31) == 0);
    float dpv = 0.f;

    for (int t = 0; t < TTOT; ++t) {
        // ---- phase 1: MFMA  gates_tile = h (16x512) * W^T (512x256) ----
        float4v acc0 = {0.f, 0.f, 0.f, 0.f};
        float4v acc1 = {0.f, 0.f, 0.f, 0.f};
        const _Float16* arow = hcur + m * HSTR + q * 8;
        #pragma unroll
        for (int kk = 0; kk < 16; ++kk) {
            half8 af = *(const half8*)(arow + kk * 32);
            acc0 = __builtin_amdgcn_mfma_f32_16x16x32_f16(af, Wf[0][kk], acc0, 0, 0, 0);
            acc1 = __builtin_amdgcn_mfma_f32_16x16x32_f16(af, Wf[1][kk], acc1, 0, 0, 0);
        }
        // ---- phase 2: stage gates to LDS (C layout: col=m, row=q*4+r) ----
        {
            const int colbase = wave * 32;
            #pragma unroll
            for (int r = 0; r < 4; ++r) {
                gates[(q * 4 + r) * GSTR + colbase +      m] = acc0[r];
                gates[(q * 4 + r) * GSTR + colbase + 16 + m] = acc1[r];
            }
        }
        // prefetch next past-input (latency hides under barrier A + phase 3)
        const int tn = t + 1;
        float xq = 0.f;
        if (tn < TPAST && tid < BW) xq = xseq[(bb * BW + tid) * TPAST + tn];

        __syncthreads();   // barrier A: gates ready; hcur reads complete

        // ---- phase 3: elementwise LSTM + h store; decoder partial deferred ----
        {
            const float xc = xcur[eb];
            const float* grow = gates + eb * GSTR;

            float gi = grow[       j0] + xc * wih_r[0][0] + bsum_r[0][0];
            float gf = grow[ 64  + j0] + xc * wih_r[0][1] + bsum_r[0][1];
            float gg = grow[128  + j0] + xc * wih_r[0][2] + bsum_r[0][2];
            float go = grow[192  + j0] + xc * wih_r[0][3] + bsum_r[0][3];
            c0 = fast_sigmoid(gf) * c0 + fast_sigmoid(gi) * fast_tanh(gg);
            const float h0 = fast_sigmoid(go) * fast_tanh(c0);

            gi = grow[       j0 + 1] + xc * wih_r[1][0] + bsum_r[1][0];
            gf = grow[ 64  + j0 + 1] + xc * wih_r[1][1] + bsum_r[1][1];
            gg = grow[128  + j0 + 1] + xc * wih_r[1][2] + bsum_r[1][2];
            go = grow[192  + j0 + 1] + xc * wih_r[1][3] + bsum_r[1][3];
            c1 = fast_sigmoid(gf) * c1 + fast_sigmoid(gi) * fast_tanh(gg);
            const float h1 = fast_sigmoid(go) * fast_tanh(c1);

            half2v hp; hp[0] = (_Float16)h0; hp[1] = (_Float16)h1;
            const unsigned int bits = __builtin_bit_cast(unsigned int, hp);
            unsigned int* hdst = hbuf
                + (size_t)((tn & 1) * BATCHN + bglob_e) * (HIDN / 2)
                + gb * (HW / 2) + jj;
            __hip_atomic_store(hdst, bits, __ATOMIC_RELAXED,
                               __HIP_MEMORY_SCOPE_AGENT);

            // decoder partial: reduce over 32 lanes (one batch row each half-wave)
            float dp = h0 * wd[0] + h1 * wd[1];
            dp += __shfl_down(dp, 16);
            dp += __shfl_down(dp, 8);
            dp += __shfl_down(dp, 4);
            dp += __shfl_down(dp, 2);
            dp += __shfl_down(dp, 1);
            dpv = dp;   // ISSUED in phase 6 so no pre-flag barrier drains it
        }

        __syncthreads();   // barrier B: all waves' h stores drained (vmcnt(0))

        if (t == TTOT - 1) {
            if (dp_lead)
                atomicAdd(out + bglob_e * TTOT + t,
                          dpv + (gb == 0 ? bdecv : 0.0f));
            break;
        }

        // ---- phase 4: arrive (1 flag store/WG) + poll (1 line, all waves) ----
        const unsigned int target = (unsigned int)tn;
        if (tid == 0)
            __hip_atomic_store(gflags + gb, target, __ATOMIC_RELAXED,
                               __HIP_MEMORY_SCOPE_AGENT);
        {
            const unsigned int* slot = gflags + (lane & 7);   // 32B, 1 line
            int guard = 0;
            for (;;) {
                const unsigned int v = __hip_atomic_load(
                    slot, __ATOMIC_RELAXED, __HIP_MEMORY_SCOPE_AGENT);
                if (__ballot(v >= target) == ~0ull) break;
                __builtin_amdgcn_s_sleep(1);
                if (++guard > (1 << 22)) break;   // fail loud, not hung
            }
        }
        __builtin_amdgcn_sched_barrier(0);   // keep reload below the spin

        // ---- phase 5: per-wave reload of its 2 rows (2 x 512 fp16) ----
        {
            const int p1 = tn & 1;
            const unsigned long long* hsrc = (const unsigned long long*)hbuf
                + (size_t)(p1 * BATCHN + bb * BW) * (HIDN / 4);
            unsigned long long* hc64 = (unsigned long long*)hcur;
            #pragma unroll
            for (int i = 0; i < 4; ++i) {
                const int idx = lane + 64 * i;       // 0..255
                const int row = 2 * wave + (idx >> 7);
                const int col = idx & 127;
                hc64[row * HSTR64 + col] =
                    __hip_atomic_load(hsrc + row * (HIDN / 4) + col,
                                      __ATOMIC_RELAXED, __HIP_MEMORY_SCOPE_AGENT);
            }
        }
        __syncthreads();   // barrier C: hcur complete

        // ---- phase 6: deferred out-atomic (drains under next MFMA) + next x ----
        if (dp_lead)
            atomicAdd(out + bglob_e * TTOT + t,
                      dpv + (gb == 0 ? bdecv : 0.0f));
        if (tn >= TPAST) {
            // x_{tn} = h_{tn}.W_dec + b_dec from fresh tile; wave w covers its
            // own rows 2w,2w+1 -> writer+readers same wave, no barrier needed.
            const _Float16* hr = hcur + eb * HSTR + jj * 16;
            const float*    wr = wdecs + jj * 16;
            float dx = 0.f;
            #pragma unroll
            for (int u = 0; u < 2; ++u) {
                half8 hv = *(const half8*)(hr + u * 8);
                #pragma unroll
                for (int e = 0; e < 8; ++e)
                    dx += (float)hv[e] * wr[u * 8 + e];
            }
            dx += __shfl_down(dx, 16);
            dx += __shfl_down(dx, 8);
            dx += __shfl_down(dx, 4);
            dx += __shfl_down(dx, 2);
            dx += __shfl_down(dx, 1);
            if (dp_lead) xcur[eb] = dx + bdecv;
        } else {
            if (tid < BW) xcur[tid] = xq;  // cross-wave reads ordered by next barrier A
        }
    }
}

extern "C" void kernel_launch(void* const* d_in, const int* in_sizes, int n_in,
                              void* d_out, int out_size, void* d_ws, size_t ws_size,
                              hipStream_t stream) {
    (void)in_sizes; (void)n_in; (void)ws_size;
    const float* xseq = (const float*)d_in[0];
    // d_in[1] = future_n scalar (fixed 64, shapes hardcoded)
    const float* Wih  = (const float*)d_in[2];
    const float* Whh  = (const float*)d_in[3];
    const float* bih  = (const float*)d_in[4];
    const float* bhh  = (const float*)d_in[5];
    const float* Wdec = (const float*)d_in[6];
    const float* bdec = (const float*)d_in[7];
    float* out = (float*)d_out;

    unsigned int* flags = (unsigned int*)d_ws;                // 16 groups x 64B
    unsigned int* hbuf  = (unsigned int*)((char*)d_ws + 8192);// [2][256][512] fp16 pairs

    hipMemsetAsync(d_ws, 0, 8192, stream);
    hipMemsetAsync(d_out, 0, (size_t)out_size * sizeof(float), stream);
    lstm_forecast_kernel<<<dim3(128), dim3(NTHR), 0, stream>>>(
        xseq, Wih, Whh, bih, bhh, Wdec, bdec, out, flags, hbuf);
}